// Round 8
// baseline (304.709 us; speedup 1.0000x reference)
//
#include <hip/hip_runtime.h>
#include <hip/hip_bf16.h>

#define BB 8
#define SS 4096
#define HH 2048
#define EE 32
#define FF 128

constexpr size_t DELTA_N = (size_t)BB * SS * HH;  // 67108864
constexpr size_t WELEM = (size_t)EE * FF * HH;    // 8388608 elems per weight tensor
constexpr size_t WBYTES = WELEM * 2;              // 16 MB packed bf16
constexpr size_t HB16_BYTES = (size_t)BB * SS * HH * 2;  // 128 MB

typedef short bf16x8 __attribute__((ext_vector_type(8)));
typedef float f32x4 __attribute__((ext_vector_type(4)));
typedef unsigned short u16;
typedef __attribute__((address_space(3))) unsigned char as3u8;
typedef __attribute__((address_space(1))) const unsigned char as1u8;

__device__ __forceinline__ u16 f2bfu(float x) {
  unsigned int u = __float_as_uint(x);
  u = (u + 0x7FFFu + ((u >> 16) & 1u)) >> 16;  // RNE
  return (u16)u;
}

__device__ __forceinline__ unsigned int pk2(float a, float b) {
  union { __hip_bfloat162 h; unsigned int u; } c;
  c.h = __float22bfloat162_rn(make_float2(a, b));
  return c.u;
}

__device__ __forceinline__ bf16x8 pack8(float4 a, float4 b) {
  union { bf16x8 v; unsigned int u[4]; } r;
  r.u[0] = pk2(a.x, a.y);
  r.u[1] = pk2(a.z, a.w);
  r.u[2] = pk2(b.x, b.y);
  r.u[3] = pk2(b.z, b.w);
  return r.v;
}

__device__ __forceinline__ uint4 cvt4(float4 a, float4 b) {
  return make_uint4(pk2(a.x, a.y), pk2(a.z, a.w), pk2(b.x, b.y), pk2(b.z, b.w));
}

__device__ __forceinline__ void glds16(const void* g, void* l) {
  __builtin_amdgcn_global_load_lds((as1u8*)g, (as3u8*)l, 16, 0, 0);
}

// ---------------- k_zero: zero n floats of ws ----------------
__global__ void k_zero(float* __restrict__ ws, int n) {
  int i = blockIdx.x * 256 + threadIdx.x;
  if (i < n) ws[i] = 0.0f;
}

// ---------------- k_pack: weights -> bf16 LDS-image order (proven) ----------------
__global__ void k_pack(const float* __restrict__ w1, const float* __restrict__ w2,
                       u16* __restrict__ w1p, u16* __restrict__ w2p) {
  unsigned c = blockIdx.x * 256 + threadIdx.x;
  const float* src;
  u16* dst;
  if (c < 1048576u) {
    unsigned e = c >> 15, ci = c & 32767u;
    unsigned it = ci >> 10;
    unsigned cb = (ci & 1023u) * 16u;
    unsigned col = cb >> 7;
    unsigned kb = (cb & 127u) ^ ((col & 7u) << 4);
    unsigned k = it * 64u + (kb >> 1);
    src = w1 + ((size_t)(e * 128u + col) * HH + k);
    dst = w1p + (size_t)c * 8;
  } else {
    unsigned c2 = c - 1048576u;
    unsigned e = c2 >> 15, ci = c2 & 32767u;
    unsigned h = ci >> 4;
    unsigned cb = (ci & 15u) * 16u;
    unsigned kb = cb ^ ((h & 7u) << 4);
    unsigned f = kb >> 1;
    src = w2 + ((size_t)(e * 2048u + h) * FF + f);
    dst = w2p + (size_t)c2 * 8;
  }
  float4 a = *(const float4*)src;
  float4 b = *(const float4*)(src + 4);
  *(bf16x8*)dst = pack8(a, b);
}

// ---------------- k_pooltile: column partial sums + bf16 swizzled hidden copy ----
// grid 512 (b = bid>>6, stile = bid&63), block 512. Each block: 64 rows x 2048 h.
__global__ __launch_bounds__(512) void k_pooltile(const float* __restrict__ hidden,
                                                  u16* __restrict__ hb16,
                                                  float* __restrict__ psum) {
  const int b  = blockIdx.x >> 6;
  const int st = blockIdx.x & 63;
  const int t  = threadIdx.x;

  const float* src = hidden + ((size_t)b * SS + st * 64) * HH + t * 4;
  char* dbase = (char*)hb16 + (size_t)(b * 64 + st) * 262144 + (size_t)(t >> 4) * 8192;
  const int kq = (t & 15) * 8;

  float4 s = make_float4(0.f, 0.f, 0.f, 0.f);
  for (int r = 0; r < 64; ++r) {
    float4 v = *(const float4*)(src + (size_t)r * HH);
    s.x += v.x; s.y += v.y; s.z += v.z; s.w += v.w;
    *(uint2*)(dbase + r * 128 + (kq ^ ((r & 7) << 4))) =
        make_uint2(pk2(v.x, v.y), pk2(v.z, v.w));
  }
  float* pp = psum + (size_t)b * HH + t * 4;
  atomicAdd(pp + 0, s.x);
  atomicAdd(pp + 1, s.y);
  atomicAdd(pp + 2, s.z);
  atomicAdd(pp + 3, s.w);
}

// ---------------- k_logits ----------------
__global__ void k_logits(const float* __restrict__ psum, const float* __restrict__ rw,
                         float* __restrict__ logits) {
  int b = blockIdx.x >> 5;
  int e = blockIdx.x & 31;
  int tid = threadIdx.x;
  float acc = 0.0f;
  const float* ps = psum + (size_t)b * HH;
  const float* wr = rw + (size_t)e * HH;
  for (int h = tid; h < HH; h += 256) acc = fmaf(ps[h], wr[h], acc);
  __shared__ float red[256];
  red[tid] = acc;
  __syncthreads();
  for (int w = 128; w > 0; w >>= 1) {
    if (tid < w) red[tid] += red[tid + w];
    __syncthreads();
  }
  if (tid == 0) logits[blockIdx.x] = red[0] * (1.0f / (float)SS);
}

// ---------------- k_topk (proven) ----------------
__global__ void k_topk(const float* __restrict__ logits, const float* __restrict__ rb,
                       const float* __restrict__ counts, const float* __restrict__ drift,
                       int* __restrict__ sel, float* __restrict__ pscale,
                       float* __restrict__ out) {
  int t = threadIdx.x;
  int b = t >> 5, e = t & 31;
  float total = 0.0f, cmax = 0.0f, dmax = 0.0f;
  for (int i = 0; i < EE; ++i) {
    float c = counts[i]; total += c; cmax = fmaxf(cmax, c);
    float d = drift[i];  dmax = fmaxf(dmax, d);
  }
  float cnt = counts[e], dr = drift[e];
  float usage = cnt / fmaxf(total, 1e-8f);
  float bonus = (total > 0.0f) ? 0.1f * (1.0f - usage) : 0.0f;
  float un = cnt / fmaxf(cmax, 1e-8f);
  float dn = dr / fmaxf(dmax, 1e-8f);
  float l = logits[t] + rb[e] + bonus - 0.05f * (un + dn);

  float m = l;
  for (int w = 16; w; w >>= 1) m = fmaxf(m, __shfl_xor(m, w, 32));
  float p = expf(l - m);
  float ssum = p;
  for (int w = 16; w; w >>= 1) ssum += __shfl_xor(ssum, w, 32);
  float prob = p / ssum;
  out[DELTA_N + 32 + t] = prob;

  float v1 = prob; int i1 = e;
  for (int w = 16; w; w >>= 1) {
    float ov = __shfl_xor(v1, w, 32); int oi = __shfl_xor(i1, w, 32);
    if (ov > v1 || (ov == v1 && oi < i1)) { v1 = ov; i1 = oi; }
  }
  float v2 = (e == i1) ? -1.0f : prob; int i2 = e;
  for (int w = 16; w; w >>= 1) {
    float ov = __shfl_xor(v2, w, 32); int oi = __shfl_xor(i2, w, 32);
    if (ov > v2 || (ov == v2 && oi < i2)) { v2 = ov; i2 = oi; }
  }
  if (e == 0) {
    float denom = fmaxf(v1 + v2, 1e-8f);
    float tp0 = v1 / denom, tp1 = v2 / denom;
    sel[b * 2 + 0] = i1;
    sel[b * 2 + 1] = i2;
    pscale[b * 2 + 0] = tp0;
    pscale[b * 2 + 1] = tp1;
    out[DELTA_N + 0 + b * 2 + 0] = (float)i1;
    out[DELTA_N + 0 + b * 2 + 1] = (float)i2;
    out[DELTA_N + 16 + b * 2 + 0] = tp0;
    out[DELTA_N + 16 + b * 2 + 1] = tp1;
  }
}

// ---------------- k_ffn2: M=64 tile, 80KB LDS, 2 blocks/CU ----------------
// grid 512: b = bid&7 (XCD), s0 = (bid>>3)*64. 512 thr = 8 waves.
// GEMM1 (waves 2x4, per-wave 32x64): M=64 N=256 K=2048, BK=64.
// GEMM2 (waves 4x2, per-wave 16x16): M=64 N=2048 K=256, n-chunk 32.
// LDS: phase1 sA dbuf [0,16K) + sB dbuf [16K,80K); phase2 sG [0,32K) + tiles [32K,64K).
// B-tile is 32KB (256 cols): waves 0-3 stage e0 half [0,16K), waves 4-7 e1 half [16K,32K)
// => dest offset wv*4096 (NOT (wv&3)*4096 — that was round 7's NaN bug).
__global__ __launch_bounds__(512, 4) void k_ffn2(
    const u16* __restrict__ hb16, const float* __restrict__ bs1,
    const float* __restrict__ bs2, const u16* __restrict__ w1p,
    const u16* __restrict__ w2p, const int* __restrict__ sel,
    const float* __restrict__ pscale, float* __restrict__ out) {
  __shared__ __align__(16) char smem[81920];

  const int t    = threadIdx.x;
  const int lane = t & 63;
  const int wv   = t >> 6;
  const int l15  = lane & 15;
  const int lk   = lane >> 4;

  const int bid = blockIdx.x;
  const int b   = bid & 7;
  const int st  = bid >> 3;

  const int e0 = sel[2 * b], e1 = sel[2 * b + 1];
  const float p0 = pscale[2 * b], p1 = pscale[2 * b + 1];

  // phase-1 wave tile
  const int wr = wv >> 2, wc = wv & 3;
  const int RB = wr * 32, CB = wc * 64;

  const char* hsrc = (const char*)hb16 + (size_t)(b * 64 + st) * 262144 + (size_t)t * 16;
  const size_t eB1 = (size_t)((wv < 4) ? e0 : e1) * 524288;
  const char* bsrc = (const char*)w1p + eB1 + (size_t)(wv & 3) * 4096 + (size_t)lane * 16;

  f32x4 zero = {0.f, 0.f, 0.f, 0.f};
  f32x4 acc1[2][4];
#pragma unroll
  for (int i = 0; i < 2; ++i)
#pragma unroll
    for (int j = 0; j < 4; ++j) acc1[i][j] = zero;

  // prologue: stage slab 0
  glds16(hsrc, &smem[(size_t)t * 16]);
#pragma unroll
  for (int r = 0; r < 4; ++r)
    glds16(bsrc + r * 1024, &smem[16384 + wv * 4096 + r * 1024 + lane * 16]);
  __syncthreads();

  // GEMM1 main loop: 32 iters x BK=64
  for (int j = 0; j < 32; ++j) {
    const int cb = j & 1, nb = cb ^ 1;
    if (j < 31) {
      glds16(hsrc + (size_t)(j + 1) * 8192, &smem[nb * 8192 + (size_t)t * 16]);
      const char* s = bsrc + (size_t)(j + 1) * 16384;
      char* d = &smem[16384 + nb * 32768 + wv * 4096 + lane * 16];
#pragma unroll
      for (int r = 0; r < 4; ++r) glds16(s + r * 1024, d + r * 1024);
    }
    const char* sa = &smem[cb * 8192];
    const char* sb = &smem[16384 + cb * 32768];
#pragma unroll
    for (int kk = 0; kk < 2; ++kk) {
      bf16x8 af[2], bv[4];
#pragma unroll
      for (int rt = 0; rt < 2; ++rt) {
        int row = RB + rt * 16 + l15;
        af[rt] = *(const bf16x8*)(sa + row * 128 + ((kk * 64 + lk * 16) ^ ((row & 7) << 4)));
      }
#pragma unroll
      for (int ct = 0; ct < 4; ++ct) {
        int col = CB + ct * 16 + l15;
        bv[ct] = *(const bf16x8*)(sb + col * 128 + ((kk * 64 + lk * 16) ^ ((col & 7) << 4)));
      }
#pragma unroll
      for (int rt = 0; rt < 2; ++rt)
#pragma unroll
        for (int ct = 0; ct < 4; ++ct)
          acc1[rt][ct] = __builtin_amdgcn_mfma_f32_16x16x32_bf16(af[rt], bv[ct], acc1[rt][ct], 0, 0, 0);
    }
    __syncthreads();
  }

  // epilogue 1: bias + exact gelu + prob scale -> sG [0,32K); also stage tiles(n0=0)
#pragma unroll
  for (int ct = 0; ct < 4; ++ct) {
    int c = CB + ct * 16 + l15;
    int ec = (c < 128) ? e0 : e1;
    float pc = (c < 128) ? p0 : p1;
    float bias = bs1[ec * FF + (c & 127)];
#pragma unroll
    for (int rt = 0; rt < 2; ++rt)
#pragma unroll
      for (int r = 0; r < 4; ++r) {
        int row = RB + rt * 16 + lk * 4 + r;
        float x = acc1[rt][ct][r] + bias;
        float g = 0.5f * x * (1.0f + erff(x * 0.70710678118654752f));
        *(u16*)&smem[row * 512 + ((c * 2) ^ ((row & 7) << 4))] = f2bfu(pc * g);
      }
  }
  // stage GEMM2 tile pair for n0=0 into buf0 [32K,48K)
  const size_t eB2 = (size_t)((wv < 4) ? e0 : e1) * 524288;
  const char* tsrc = (const char*)w2p + eB2 + (size_t)(wv & 3) * 2048 + (size_t)lane * 16;
  {
    char* d = &smem[32768 + (wv >> 2) * 8192 + (wv & 3) * 2048 + lane * 16];
#pragma unroll
    for (int i = 0; i < 2; ++i) glds16(tsrc + i * 1024, d + i * 1024);
  }
  __syncthreads();

  // GEMM2: per-wave 16 rows x 16 cols; preload A frags (8 x bf16x8 = 32 VGPR)
  const int wr2 = wv & 3, wc2 = wv >> 2;
  bf16x8 pa[8];
  {
    int row = wr2 * 16 + l15;
    unsigned sw = (row & 7) << 4;
#pragma unroll
    for (int ks = 0; ks < 8; ++ks)
      pa[ks] = *(const bf16x8*)&smem[row * 512 + ((ks * 64 + lk * 16) ^ sw)];
  }

  float* obase = out + ((size_t)b * SS + st * 64) * HH;
  const int hin = wc2 * 16 + l15;  // 0..31 within n-chunk

#pragma unroll 1
  for (int n0 = 0; n0 < 64; ++n0) {
    const int cb = n0 & 1, nb = cb ^ 1;
    if (n0 < 63) {
      const char* s = tsrc + (size_t)(n0 + 1) * 8192;
      char* d = &smem[32768 + nb * 16384 + (wv >> 2) * 8192 + (wv & 3) * 2048 + lane * 16];
#pragma unroll
      for (int i = 0; i < 2; ++i) glds16(s + i * 1024, d + i * 1024);
    }
    f32x4 acc2 = zero;
    const char* tb = &smem[32768 + cb * 16384];
#pragma unroll
    for (int ks = 0; ks < 8; ++ks) {
      bf16x8 bv = *(const bf16x8*)(tb + (ks >> 2) * 8192 + hin * 256 +
                                   (((ks & 3) * 64 + lk * 16) ^ ((hin & 7) << 4)));
      acc2 = __builtin_amdgcn_mfma_f32_16x16x32_bf16(pa[ks], bv, acc2, 0, 0, 0);
    }
    const int h = n0 * 32 + hin;
    float bias = p0 * bs2[(size_t)e0 * HH + h] + p1 * bs2[(size_t)e1 * HH + h];
#pragma unroll
    for (int r = 0; r < 4; ++r) {
      int row = wr2 * 16 + lk * 4 + r;
      obase[(size_t)row * HH + h] = acc2[r] + bias;
    }
    __syncthreads();
  }
}

// ================= fallback paths =================
__global__ void k_pool_logits(const float* __restrict__ hidden,
                              const float* __restrict__ rw,
                              float* __restrict__ logits) {
  const int b  = blockIdx.x >> 6;
  const int hc = (blockIdx.x >> 3) & 7;
  const int sq = blockIdx.x & 7;
  const int t  = threadIdx.x;
  const int tx = t & 63;
  const int qq = t >> 6;
  const int h0 = hc * 256;

  const float* p = hidden + ((size_t)b * SS + sq * 512 + qq * 128) * HH + h0 + tx * 4;
  float4 s = make_float4(0.f, 0.f, 0.f, 0.f);
  for (int i = 0; i < 128; ++i) {
    float4 v = *(const float4*)(p + (size_t)i * HH);
    s.x += v.x; s.y += v.y; s.z += v.z; s.w += v.w;
  }
  __shared__ float ps[4][256];
  __shared__ float pl[256];
  *(float4*)&ps[qq][tx * 4] = s;
  __syncthreads();
  pl[t] = ps[0][t] + ps[1][t] + ps[2][t] + ps[3][t];
  __syncthreads();

  const int e = t >> 3, part = t & 7;
  const float* wrp = rw + (size_t)e * HH + h0 + part * 32;
  float v = 0.f;
#pragma unroll
  for (int m = 0; m < 32; ++m) v += pl[part * 32 + m] * wrp[m];
  v += __shfl_xor(v, 1, 8);
  v += __shfl_xor(v, 2, 8);
  v += __shfl_xor(v, 4, 8);
  if (part == 0) atomicAdd(&logits[b * EE + e], v * (1.0f / (float)SS));
}

__global__ __launch_bounds__(512, 2) void k_ffn_mid(
    const float* __restrict__ hidden, const float* __restrict__ bs1,
    const float* __restrict__ bs2, const u16* __restrict__ w1p,
    const u16* __restrict__ w2p, const int* __restrict__ sel,
    const float* __restrict__ pscale, float* __restrict__ out) {
  __shared__ __align__(16) char smem[131072];

  const int t    = threadIdx.x;
  const int lane = t & 63;
  const int wv   = t >> 6;
  const int wr   = wv >> 2;
  const int wc   = wv & 3;
  const int l15  = lane & 15;
  const int lk   = lane >> 4;

  const int bid = blockIdx.x;
  const int b   = bid & 7;
  const int s0  = (bid >> 3) * 128;

  const int e0 = sel[2 * b], e1 = sel[2 * b + 1];
  const float p0 = pscale[2 * b], p1 = pscale[2 * b + 1];

  const int RB  = wr * 64;
  const int CBc = wc * 64;
  const int CB2 = wc * 32;

  const char* w1pb = (const char*)w1p;
  const char* w2pb = (const char*)w2p;

  const int arow = t >> 2;
  const int akq2 = (t & 3) * 32;
  const float* hA = hidden + ((size_t)b * SS + s0 + arow) * HH + (t & 3) * 16;
  const unsigned swA = (arow & 7) << 4;

  const size_t esel = (size_t)(wv < 4 ? e0 : e1);
  const char* w1src = w1pb + esel * 524288 + (size_t)(wv & 3) * 4096 + (size_t)lane * 16;
  char* sbW = &smem[32768 + wv * 4096];

  f32x4 zero = {0.f, 0.f, 0.f, 0.f};
  f32x4 acc1[4][4];
#pragma unroll
  for (int i = 0; i < 4; ++i)
#pragma unroll
    for (int j = 0; j < 4; ++j) acc1[i][j] = zero;

  {
    float4 P[4];
#pragma unroll
    for (int q = 0; q < 4; ++q) P[q] = *(const float4*)(hA + q * 4);
#pragma unroll
    for (int r = 0; r < 4; ++r) glds16(w1src + r * 1024, sbW + r * 1024);
    char* da = &smem[arow * 128];
    *(uint4*)(da + (akq2 ^ swA)) = cvt4(P[0], P[1]);
    *(uint4*)(da + ((akq2 + 16) ^ swA)) = cvt4(P[2], P[3]);
  }
  __syncthreads();

  for (int j = 0; j < 32; ++j) {
    const int cb = j & 1, nb = cb ^ 1;
    float4 P[4];
    if (j < 31) {
      const float* hp = hA + (j + 1) * 64;
#pragma unroll
      for (int q = 0; q < 4; ++q) P[q] = *(const float4*)(hp + q * 4);
      const char* s = w1src + (size_t)(j + 1) * 16384;
      char* d = sbW + nb * 32768;
#pragma unroll
      for (int r = 0; r < 4; ++r) glds16(s + r * 1024, d + r * 1024);
    }
    const char* sa = &smem[cb * 16384];
    const char* sb = &smem[32768 + cb * 32768];
#pragma unroll
    for (int kk = 0; kk < 2; ++kk) {
      bf16x8 af[4], bfv[4];
#pragma unroll
      for (int rt = 0; rt < 4; ++rt) {
        int row = RB + rt * 16 + l15;
        af[rt] = *(const bf16x8*)(sa + row * 128 + ((kk * 64 + lk * 16) ^ ((row & 7) << 4)));
      }
#pragma unroll
      for (int ct = 0; ct < 4; ++ct) {
        int col = CBc + ct * 16 + l15;
        bfv[ct] = *(const bf16x8*)(sb + col * 128 + ((kk * 64 + lk * 16) ^ ((col & 7) << 4)));
      }
#pragma unroll
      for (int rt = 0; rt < 4; ++rt)
#pragma unroll
        for (int ct = 0; ct < 4; ++ct)
          acc1[rt][ct] = __builtin_amdgcn_mfma_f32_16x16x32_bf16(af[rt], bfv[ct], acc1[rt][ct], 0, 0, 0);
    }
    if (j < 31) {
      char* da = &smem[nb * 16384 + arow * 128];
      *(uint4*)(da + (akq2 ^ swA)) = cvt4(P[0], P[1]);
      *(uint4*)(da + ((akq2 + 16) ^ swA)) = cvt4(P[2], P[3]);
    }
    __syncthreads();
  }

#pragma unroll
  for (int ct = 0; ct < 4; ++ct) {
    int c = CBc + ct * 16 + l15;
    int ec = (c < 128) ? e0 : e1;
    float pc = (c < 128) ? p0 : p1;
    float bias = bs1[ec * FF + (c & 127)];
#pragma unroll
    for (int rt = 0; rt < 4; ++rt)
#pragma unroll
      for (int r = 0; r < 4; ++r) {
        int row = RB + rt * 16 + lk * 4 + r;
        float x = acc1[rt][ct][r] + bias;
        float g = 0.5f * x * (1.0f + erff(x * 0.70710678118654752f));
        *(u16*)&smem[row * 512 + ((c * 2) ^ ((row & 7) << 4))] = f2bfu(pc * g);
      }
  }
  {
    const char* s = w2pb + (size_t)e0 * 524288 + (size_t)wv * 4096 + (size_t)lane * 16;
    char* d = &smem[65536 + wv * 4096];
#pragma unroll
    for (int r = 0; r < 4; ++r) glds16(s + r * 1024, d + r * 1024);
  }
  __syncthreads();

  bf16x8 pa[4][8];
#pragma unroll
  for (int rt = 0; rt < 4; ++rt) {
    int row = RB + rt * 16 + l15;
    unsigned sw = (row & 7) << 4;
#pragma unroll
    for (int ks = 0; ks < 8; ++ks)
      pa[rt][ks] = *(const bf16x8*)&smem[row * 512 + ((ks * 64 + lk * 16) ^ sw)];
  }

  float* obase = out + ((size_t)b * SS + s0) * HH;
  const char* gsrc_w = w2pb + (size_t)wv * 4096 + (size_t)lane * 16;

#pragma unroll 1
  for (int n0 = 0; n0 < 16; ++n0) {
    f32x4 acc2[4][2];
#pragma unroll
    for (int i = 0; i < 4; ++i) { acc2[i][0] = zero; acc2[i][1] = zero; }
    {
      const char* s = gsrc_w + (size_t)e1 * 524288 + (size_t)n0 * 32768;
      char* d = &smem[65536 + 32768 + wv * 4096];
#pragma unroll
      for (int r = 0; r < 4; ++r) glds16(s + r * 1024, d + r * 1024);
    }
    {
      const char* tb = &smem[65536];
#pragma unroll
      for (int ks = 0; ks < 4; ++ks) {
        bf16x8 bfv[2];
#pragma unroll
        for (int ct = 0; ct < 2; ++ct) {
          int col = CB2 + ct * 16 + l15;
          bfv[ct] = *(const bf16x8*)(tb + col * 256 + ((ks * 64 + lk * 16) ^ ((col & 7) << 4)));
        }
#pragma unroll
        for (int rt = 0; rt < 4; ++rt)
#pragma unroll
          for (int ct = 0; ct < 2; ++ct)
            acc2[rt][ct] = __builtin_amdgcn_mfma_f32_16x16x32_bf16(pa[rt][ks], bfv[ct], acc2[rt][ct], 0, 0, 0);
      }
    }
    __syncthreads();
    if (n0 < 15) {
      const char* s = gsrc_w + (size_t)e0 * 524288 + (size_t)(n0 + 1) * 32768;
      char* d = &smem[65536 + wv * 4096];
#pragma unroll
      for (int r = 0; r < 4; ++r) glds16(s + r * 1024, d + r * 1024);
    }
    {
      const char* tb = &smem[65536 + 32768];
#pragma unroll
      for (int ks = 0; ks < 4; ++ks) {
        bf16x8 bfv[2];
#pragma unroll
        for (int ct = 0; ct < 2; ++ct) {
          int col = CB2 + ct * 16 + l15;
          bfv[ct] = *(const bf16x8*)(tb + col * 256 + ((ks * 64 + lk * 16) ^ ((col & 7) << 4)));
        }
#pragma unroll
        for (int rt = 0; rt < 4; ++rt)
#pragma unroll
          for (int ct = 0; ct < 2; ++ct)
            acc2[rt][ct] = __builtin_amdgcn_mfma_f32_16x16x32_bf16(pa[rt][4 + ks], bfv[ct], acc2[rt][ct], 0, 0, 0);
      }
    }
#pragma unroll
    for (int ct = 0; ct < 2; ++ct) {
      int h = n0 * 128 + CB2 + ct * 16 + l15;
      float bias = p0 * bs2[(size_t)e0 * HH + h] + p1 * bs2[(size_t)e1 * HH + h];
#pragma unroll
      for (int rt = 0; rt < 4; ++rt)
#pragma unroll
        for (int r = 0; r < 4; ++r) {
          int row = RB + rt * 16 + lk * 4 + r;
          obase[(size_t)row * HH + h] = acc2[rt][ct][r] + bias;
        }
    }
    __syncthreads();
  }
}

extern "C" void kernel_launch(void* const* d_in, const int* in_sizes, int n_in,
                              void* d_out, int out_size, void* d_ws, size_t ws_size,
                              hipStream_t stream) {
  const float* hidden   = (const float*)d_in[0];
  const float* router_w = (const float*)d_in[1];
  const float* router_b = (const float*)d_in[2];
  const float* w1       = (const float*)d_in[3];
  const float* b1       = (const float*)d_in[4];
  const float* w2       = (const float*)d_in[5];
  const float* b2       = (const float*)d_in[6];
  const float* counts   = (const float*)d_in[7];
  const float* drift    = (const float*)d_in[8];
  float* out            = (float*)d_out;

  float* logits = (float*)d_ws;                     // 256 f @ 0
  int*   sel    = (int*)((char*)d_ws + 1024);       // 16 int
  float* pscale = (float*)((char*)d_ws + 1088);     // 16 f
  float* psum   = (float*)((char*)d_ws + 4096);     // BB*HH f (64KB)

  const size_t need_big = 131072 + 2 * WBYTES + HB16_BYTES;
  const size_t need_mid = 4096 + 2 * WBYTES + 64;

  if (ws_size >= need_big) {
    u16* w1p  = (u16*)((char*)d_ws + 131072);
    u16* w2p  = (u16*)((char*)d_ws + 131072 + WBYTES);
    u16* hb16 = (u16*)((char*)d_ws + 131072 + 2 * WBYTES);
    k_zero<<<68, 256, 0, stream>>>(logits, 17408);
    k_pack<<<8192, 256, 0, stream>>>(w1, w2, w1p, w2p);
    k_pooltile<<<512, 512, 0, stream>>>(hidden, hb16, psum);
    k_logits<<<256, 256, 0, stream>>>(psum, router_w, logits);
    k_topk<<<1, 256, 0, stream>>>(logits, router_b, counts, drift, sel, pscale, out);
    k_ffn2<<<512, 512, 0, stream>>>(hb16, b1, b2, w1p, w2p, sel, pscale, out);
  } else if (ws_size >= need_mid) {
    u16* w1p = (u16*)((char*)d_ws + 4096);
    u16* w2p = (u16*)((char*)d_ws + 4096 + WBYTES);
    k_zero<<<2, 256, 0, stream>>>(logits, 288);
    k_pack<<<8192, 256, 0, stream>>>(w1, w2, w1p, w2p);
    k_pool_logits<<<512, 256, 0, stream>>>(hidden, router_w, logits);
    k_topk<<<1, 256, 0, stream>>>(logits, router_b, counts, drift, sel, pscale, out);
    k_ffn_mid<<<256, 512, 0, stream>>>(hidden, b1, b2, w1p, w2p, sel, pscale, out);
  }
}